// Round 3
// baseline (144.357 us; speedup 1.0000x reference)
//
#include <hip/hip_runtime.h>

#define HH 128
#define WW 128
#define NPIX 16384
#define NC 32
#define NO 32
#define KS 9
#define TAPS 81
#define DIL 2
#define PAD 8
#define SMAX 27.6310211159f   // s <= SMAX <=> exp(-0.5 s) >= 1e-6; dropped-tap bound ~1.4e-5 << tol
#define CAP 262144            // sparse-list capacity (expected ~3000 entries)

// ---------------------------------------------------------------------------
// dense_center: out[o][pix] = bias[o] + sum_c in[c][pix] * W[o][c][4][4].
// Center tap of the dilated patch is the pixel itself and k_center = exp(0)=1
// exactly, so this is an exact dense 1x1 conv — no kbuf, no masks, no
// divergence. Weight index (o*NC+c)*TAPS+40 is wave-uniform -> s_loads.
// Layer-1 call also zeroes the sparse-list counter (cnt != nullptr), so no
// hipMemset is needed and prep (next dispatch in-stream) sees cnt==0.
// ---------------------------------------------------------------------------
__global__ __launch_bounds__(256) void dense_center(
    const float* __restrict__ in, const float* __restrict__ W,
    const float* __restrict__ bias, float* __restrict__ out,
    unsigned* __restrict__ cnt)
{
    if (cnt && blockIdx.x == 0 && blockIdx.y == 0 && threadIdx.x == 0) *cnt = 0u;
    const int pix = blockIdx.x * 256 + threadIdx.x;
    const int o0 = blockIdx.y * 4;

    float x0[NC];
#pragma unroll
    for (int c = 0; c < NC; ++c) x0[c] = in[c * NPIX + pix];

    float a0 = 0.f, a1 = 0.f, a2 = 0.f, a3 = 0.f;
#pragma unroll
    for (int c = 0; c < NC; ++c) {
        float xv = x0[c];
        a0 = fmaf(xv, W[((o0 + 0) * NC + c) * TAPS + 40], a0);
        a1 = fmaf(xv, W[((o0 + 1) * NC + c) * TAPS + 40], a1);
        a2 = fmaf(xv, W[((o0 + 2) * NC + c) * TAPS + 40], a2);
        a3 = fmaf(xv, W[((o0 + 3) * NC + c) * TAPS + 40], a3);
    }
    out[(o0 + 0) * NPIX + pix] = a0 + bias[o0 + 0];
    out[(o0 + 1) * NPIX + pix] = a1 + bias[o0 + 1];
    out[(o0 + 2) * NPIX + pix] = a2 + bias[o0 + 2];
    out[(o0 + 3) * NPIX + pix] = a3 + bias[o0 + 3];
}

// ---------------------------------------------------------------------------
// prep_list: per (i,pix) compute s for the 9 j's; every live non-center tap
// (valid, s<=SMAX) appends one compacted entry {pix|T<<14, exp(-0.5 s)} via
// atomicAdd on cnt (~3000 entries total, ~0.002 hit rate -> negligible
// contention). No kbuf, no mask arrays, no weight transpose.
// OOB taps contribute exactly 0 (x zero-padded) -> dropped exactly.
// ---------------------------------------------------------------------------
__global__ __launch_bounds__(256) void prep_list(
    const float* __restrict__ f, unsigned* __restrict__ cnt,
    unsigned* __restrict__ meta, float* __restrict__ kvl)
{
    const int i = blockIdx.y;
    const int pix = blockIdx.x * 256 + threadIdx.x;
    const int h = pix >> 7, w = pix & (WW - 1);

    float fc[NC];
#pragma unroll
    for (int c = 0; c < NC; ++c) fc[c] = f[c * NPIX + pix];

    const int qh = h + i * DIL - PAD;
    const bool vh = (unsigned)qh < HH;
#pragma unroll
    for (int j = 0; j < KS; ++j) {
        int qw = w + j * DIL - PAD;
        bool valid = vh & ((unsigned)qw < WW);
        int q = valid ? (qh * WW + qw) : pix;   // safe addr for masked lanes
        float s0 = 0.f, s1 = 0.f, s2 = 0.f, s3 = 0.f;
#pragma unroll
        for (int c4 = 0; c4 < 8; ++c4) {
            float d0 = f[(4 * c4 + 0) * NPIX + q] - fc[4 * c4 + 0];
            float d1 = f[(4 * c4 + 1) * NPIX + q] - fc[4 * c4 + 1];
            float d2 = f[(4 * c4 + 2) * NPIX + q] - fc[4 * c4 + 2];
            float d3 = f[(4 * c4 + 3) * NPIX + q] - fc[4 * c4 + 3];
            s0 = fmaf(d0, d0, s0); s1 = fmaf(d1, d1, s1);
            s2 = fmaf(d2, d2, s2); s3 = fmaf(d3, d3, s3);
        }
        float s = (s0 + s1) + (s2 + s3);
        bool live = valid && (s <= SMAX) && !(i == 4 && j == 4);
        if (live) {
            unsigned idx = atomicAdd(cnt, 1u);
            if (idx < CAP) {
                meta[idx] = (unsigned)pix | ((unsigned)(i * KS + j) << 14);
                kvl[idx] = __expf(-0.5f * s);
            }
        }
    }
}

// ---------------------------------------------------------------------------
// sparse_resid: one work-item per (entry, o) — 32 consecutive lanes share an
// entry, so the in[c][q] loads are broadcast (1-2 lines per instr). Adds
// kv * sum_c in[c][q] * W[o][c][T] into out[o][pix] via device-scope float
// atomics (entries for the same pixel may collide; atomics handle it).
// Grid-stride over n*32 so any list size is covered.
// ---------------------------------------------------------------------------
__global__ __launch_bounds__(256) void sparse_resid(
    const float* __restrict__ in, const float* __restrict__ W,
    const unsigned* __restrict__ cnt, const unsigned* __restrict__ meta,
    const float* __restrict__ kvl, float* __restrict__ out)
{
    unsigned n = *cnt;
    if (n > CAP) n = CAP;
    const unsigned total = n * 32u;
    for (unsigned it = blockIdx.x * 256 + threadIdx.x; it < total;
         it += gridDim.x * 256) {
        unsigned e = it >> 5;
        int o = (int)(it & 31u);
        unsigned m = meta[e];
        int pix = (int)(m & 16383u);
        int T = (int)(m >> 14);
        int ii = T / KS, jj = T - KS * ii;
        int q = pix + (ii * DIL - PAD) * WW + (jj * DIL - PAD);
        float kv = kvl[e];
        const float* __restrict__ wp = W + o * (NC * TAPS) + T;   // [o][c][T]
        float t0 = 0.f, t1 = 0.f, t2 = 0.f, t3 = 0.f;
#pragma unroll
        for (int c4 = 0; c4 < 8; ++c4) {
            t0 = fmaf(in[(4 * c4 + 0) * NPIX + q], wp[(4 * c4 + 0) * TAPS], t0);
            t1 = fmaf(in[(4 * c4 + 1) * NPIX + q], wp[(4 * c4 + 1) * TAPS], t1);
            t2 = fmaf(in[(4 * c4 + 2) * NPIX + q], wp[(4 * c4 + 2) * TAPS], t2);
            t3 = fmaf(in[(4 * c4 + 3) * NPIX + q], wp[(4 * c4 + 3) * TAPS], t3);
        }
        atomicAdd(&out[o * NPIX + pix], kv * ((t0 + t1) + (t2 + t3)));
    }
}

// ---------------------------------------------------------------------------
// Fallback (proven path, 2 MB ws) in case ws is small. Takes W in original
// [o][c][tap] layout.
// ---------------------------------------------------------------------------
#define CHUNK 27
#define NCHUNK 3
#define KMIN 1e-6f
__global__ __launch_bounds__(256) void pac_layer_fuse(
    const float* __restrict__ in, const float* __restrict__ f,
    const float* __restrict__ Wt, const float* __restrict__ bias,
    float* __restrict__ out)
{
    __shared__ float wl[NC * CHUNK * 8];
    const int og = blockIdx.y;
    const int pix = blockIdx.x * 256 + threadIdx.x;
    const int h = pix >> 7, w = pix & (WW - 1);
    float acc[8];
#pragma unroll
    for (int i = 0; i < 8; ++i) acc[i] = 0.f;
    float fc[NC];
#pragma unroll
    for (int c = 0; c < NC; ++c) fc[c] = f[c * NPIX + pix];
    for (int ch = 0; ch < NCHUNK; ++ch) {
        __syncthreads();
        for (int idx = threadIdx.x; idx < NC * CHUNK * 8; idx += 256) {
            int t = idx % CHUNK;
            int c = (idx / CHUNK) % NC;
            int o = idx / (CHUNK * NC);
            wl[(c * CHUNK + t) * 8 + o] =
                Wt[(og * 8 + o) * (NC * TAPS) + c * TAPS + ch * CHUNK + t];
        }
        __syncthreads();
        for (int t = 0; t < CHUNK; ++t) {
            int tap = ch * CHUNK + t;
            int qh = h + (tap / KS) * DIL - PAD;
            int qw = w + (tap % KS) * DIL - PAD;
            bool valid = ((unsigned)qh < HH) & ((unsigned)qw < WW);
            int q = qh * WW + qw;
            float s = 0.f;
#pragma unroll
            for (int c = 0; c < NC; ++c) {
                float fn = valid ? f[c * NPIX + q] : 0.f;
                float d = fn - fc[c];
                s = fmaf(d, d, s);
            }
            float kv = __expf(-0.5f * s);
            if (__all((kv < KMIN) | (!valid))) continue;
            const float* wpp = &wl[t * 8];
#pragma unroll 8
            for (int c = 0; c < NC; ++c) {
                float v = valid ? in[c * NPIX + q] : 0.f;
                v *= kv;
#pragma unroll
                for (int o = 0; o < 8; ++o)
                    acc[o] = fmaf(v, wpp[c * CHUNK * 8 + o], acc[o]);
            }
        }
    }
#pragma unroll
    for (int o = 0; o < 8; ++o)
        out[(og * 8 + o) * NPIX + pix] = acc[o] + bias[og * 8 + o];
}

// ---------------------------------------------------------------------------
extern "C" void kernel_launch(void* const* d_in, const int* in_sizes, int n_in,
                              void* d_out, int out_size, void* d_ws, size_t ws_size,
                              hipStream_t stream)
{
    (void)in_sizes; (void)n_in; (void)out_size;
    const float* x  = (const float*)d_in[0];
    const float* f  = (const float*)d_in[1];
    const float* W1 = (const float*)d_in[2];
    const float* b1 = (const float*)d_in[3];
    const float* W2 = (const float*)d_in[4];
    const float* b2 = (const float*)d_in[5];
    float* out = (float*)d_out;

    float* ws = (float*)d_ws;
    float* hbufm = ws;                                     // NO*NPIX floats
    unsigned* cnt  = (unsigned*)(ws + NO * NPIX);          // 4 u32 (aligned)
    unsigned* meta = cnt + 4;                              // CAP u32
    float* kvl = (float*)(meta + CAP);                     // CAP f32
    const size_t need = (size_t)(NO * NPIX + 4 + 2 * CAP) * 4;

    if (ws_size >= need) {
        // dense1 also zeroes cnt (in-stream, before prep's atomics)
        dense_center<<<dim3(64, 8), 256, 0, stream>>>(x, W1, b1, hbufm, cnt);
        prep_list<<<dim3(64, KS), 256, 0, stream>>>(f, cnt, meta, kvl);
        sparse_resid<<<dim3(384), 256, 0, stream>>>(x, W1, cnt, meta, kvl, hbufm);
        dense_center<<<dim3(64, 8), 256, 0, stream>>>(hbufm, W2, b2, out, nullptr);
        sparse_resid<<<dim3(384), 256, 0, stream>>>(hbufm, W2, cnt, meta, kvl, out);
    } else {
        float* hbuf = ws;
        pac_layer_fuse<<<dim3(64, 4), 256, 0, stream>>>(x, f, W1, b1, hbuf);
        pac_layer_fuse<<<dim3(64, 4), 256, 0, stream>>>(hbuf, f, W2, b2, out);
    }
}

// Round 5
// 126.890 us; speedup vs baseline: 1.1377x; 1.1377x over previous
//
#include <hip/hip_runtime.h>

#define HH 128
#define WW 128
#define NPIX 16384
#define NC 32
#define NO 32
#define KS 9
#define TAPS 81
#define DIL 2
#define PAD 8
#define SMAX 27.6310211159f   // s <= SMAX <=> exp(-0.5 s) >= 1e-6; dropped-tap bound ~1.4e-5 << tol
#define NW (NO * NC * TAPS)   // 82944
#define CAP 262144            // sparse-list capacity (expected ~3000 entries)

// ---------------------------------------------------------------------------
// zero_cnt: 1-node counter init (graph-capture-safe kernel, not memset).
// Must be its own dispatch BEFORE front_kernel: prep blocks may run before
// any other block under undefined dispatch order.
// ---------------------------------------------------------------------------
__global__ __launch_bounds__(64) void zero_cnt_kernel(unsigned* __restrict__ cnt)
{
    if (threadIdx.x == 0) *cnt = 0u;
}

// ---------------------------------------------------------------------------
// sparse_body: one 32-lane group per list entry (o = lane within group).
// list entry = {pix | T<<14, kv}. Weights from transposed Wt[tap][o][c] ->
// per-lane contiguous 32 floats = 8x dwordx4. in[c][q] loads broadcast
// (same addr across the 32 lanes). Adds kv * dot into out via f32 atomics
// (out pre-zeroed / written-by-atomics only -> order-independent).
// ---------------------------------------------------------------------------
__device__ __forceinline__ void sparse_body(
    const float* __restrict__ in, const float* __restrict__ Wt,
    const unsigned* __restrict__ cnt, const uint2* __restrict__ list,
    float* __restrict__ out, unsigned gid, unsigned stride)
{
    unsigned n = *cnt;
    if (n > CAP) n = CAP;
    const unsigned total = n * 32u;
    for (unsigned it = gid; it < total; it += stride) {
        unsigned e = it >> 5;
        int o = (int)(it & 31u);
        uint2 me = list[e];
        int pix = (int)(me.x & 16383u);
        int T = (int)(me.x >> 14);
        float kv = __uint_as_float(me.y);
        int ii = T / KS, jj = T - KS * ii;
        int q = pix + (ii * DIL - PAD) * WW + (jj * DIL - PAD);
        const float4* __restrict__ wp =
            (const float4*)(Wt + (T * NO + o) * NC);
        float t0 = 0.f, t1 = 0.f, t2 = 0.f, t3 = 0.f;
#pragma unroll
        for (int c4 = 0; c4 < 8; ++c4) {
            float4 w4 = wp[c4];
            t0 = fmaf(in[(4 * c4 + 0) * NPIX + q], w4.x, t0);
            t1 = fmaf(in[(4 * c4 + 1) * NPIX + q], w4.y, t1);
            t2 = fmaf(in[(4 * c4 + 2) * NPIX + q], w4.z, t2);
            t3 = fmaf(in[(4 * c4 + 3) * NPIX + q], w4.w, t3);
        }
        atomicAdd(&out[o * NPIX + pix], kv * ((t0 + t1) + (t2 + t3)));
    }
}

// ---------------------------------------------------------------------------
// K1 (front): all mutually-independent work in ONE dispatch, role by blockIdx.y:
//   y in [0,41): prep, taps {2y, 2y+1} per block (fc amortized over the pair),
//                2624 blocks ~= 10 waves/SIMD; live taps append to list via
//                per-lane atomicAdd (~3000 total, negligible contention).
//   y in [41,49): dense1 -> h = bias1 + W1[.,.,4,4] (1x1 conv, exact center,
//                kv=1). Weights staged via LDS (parallel vector gather ->
//                broadcast ds_read) instead of a serial cold s_load chain.
//   y == 49: zero d_out (for K3's all-atomic accumulation).
//   y == 50: transpose W1,W2 -> [tap][o][c] for the sparse path.
// ---------------------------------------------------------------------------
__global__ __launch_bounds__(256) void front_kernel(
    const float* __restrict__ x, const float* __restrict__ f,
    const float* __restrict__ W1, const float* __restrict__ W2,
    const float* __restrict__ b1,
    float* __restrict__ h, unsigned* __restrict__ cnt,
    uint2* __restrict__ list, float* __restrict__ W1t,
    float* __restrict__ W2t, float* __restrict__ outz)
{
    const int y = blockIdx.y;
    const int tid = threadIdx.x;

    if (y < 41) {                               // ---- prep: taps 2y, 2y+1
        const int pix = blockIdx.x * 256 + tid;
        const int hh = pix >> 7, ww = pix & (WW - 1);
        float fc[NC];
#pragma unroll
        for (int c = 0; c < NC; ++c) fc[c] = f[c * NPIX + pix];
#pragma unroll
        for (int u = 0; u < 2; ++u) {
            int T = 2 * y + u;
            if (T >= TAPS || T == 40) continue;  // center handled densely
            int ii = T / KS, jj = T - KS * ii;
            int qh = hh + ii * DIL - PAD;
            int qw = ww + jj * DIL - PAD;
            bool valid = ((unsigned)qh < HH) & ((unsigned)qw < WW);
            int q = valid ? (qh * WW + qw) : pix;   // safe addr for masked lanes
            float s0 = 0.f, s1 = 0.f, s2 = 0.f, s3 = 0.f;
#pragma unroll
            for (int c4 = 0; c4 < 8; ++c4) {
                float d0 = f[(4 * c4 + 0) * NPIX + q] - fc[4 * c4 + 0];
                float d1 = f[(4 * c4 + 1) * NPIX + q] - fc[4 * c4 + 1];
                float d2 = f[(4 * c4 + 2) * NPIX + q] - fc[4 * c4 + 2];
                float d3 = f[(4 * c4 + 3) * NPIX + q] - fc[4 * c4 + 3];
                s0 = fmaf(d0, d0, s0); s1 = fmaf(d1, d1, s1);
                s2 = fmaf(d2, d2, s2); s3 = fmaf(d3, d3, s3);
            }
            float s = (s0 + s1) + (s2 + s3);
            // OOB taps contribute exactly 0 (x zero-padded) -> drop exactly.
            if (valid && (s <= SMAX)) {
                unsigned idx = atomicAdd(cnt, 1u);
                if (idx < CAP)
                    list[idx] = make_uint2(
                        (unsigned)pix | ((unsigned)T << 14),
                        __float_as_uint(__expf(-0.5f * s)));
            }
        }
        return;
    }

    if (y < 49) {                               // ---- dense1 -> h
        const int o0 = (y - 41) * 4;
        __shared__ float wsm[4 * NC];
        if (tid < 128) {
            int o = tid >> 5, c = tid & 31;
            wsm[tid] = W1[((o0 + o) * NC + c) * TAPS + 40];
        }
        __syncthreads();
        const int pix = blockIdx.x * 256 + tid;
        float x0[NC];
#pragma unroll
        for (int c = 0; c < NC; ++c) x0[c] = x[c * NPIX + pix];
        float a0 = 0.f, a1 = 0.f, a2 = 0.f, a3 = 0.f;
#pragma unroll
        for (int c = 0; c < NC; ++c) {
            float xv = x0[c];
            a0 = fmaf(xv, wsm[0 * NC + c], a0);
            a1 = fmaf(xv, wsm[1 * NC + c], a1);
            a2 = fmaf(xv, wsm[2 * NC + c], a2);
            a3 = fmaf(xv, wsm[3 * NC + c], a3);
        }
        h[(o0 + 0) * NPIX + pix] = a0 + b1[o0 + 0];
        h[(o0 + 1) * NPIX + pix] = a1 + b1[o0 + 1];
        h[(o0 + 2) * NPIX + pix] = a2 + b1[o0 + 2];
        h[(o0 + 3) * NPIX + pix] = a3 + b1[o0 + 3];
        return;
    }

    if (y == 49) {                              // ---- zero d_out
        float4 z = make_float4(0.f, 0.f, 0.f, 0.f);
        for (int t = blockIdx.x * 256 + tid; t < (NO * NPIX) / 4; t += 64 * 256)
            ((float4*)outz)[t] = z;
        return;
    }

    // ---- y == 50: weight transpose [o][c][tap] -> [tap][o][c]
    for (int t = blockIdx.x * 256 + tid; t < NW; t += 64 * 256) {
        int o = t / (NC * TAPS);
        int r = t - o * (NC * TAPS);
        int c = r / TAPS;
        int tap = r - c * TAPS;
        int d = (tap * NO + o) * NC + c;
        W1t[d] = W1[t];
        W2t[d] = W2[t];
    }
}

// ---------------------------------------------------------------------------
// K2: sparse residual of layer 1 into h (h already holds dense1+bias).
// ---------------------------------------------------------------------------
__global__ __launch_bounds__(256) void sparse1_kernel(
    const float* __restrict__ x, const float* __restrict__ W1t,
    const unsigned* __restrict__ cnt, const uint2* __restrict__ list,
    float* __restrict__ h)
{
    sparse_body(x, W1t, cnt, list, h,
                blockIdx.x * 256 + threadIdx.x, gridDim.x * 256);
}

// ---------------------------------------------------------------------------
// K3 (back): dense2 + sparse2 fused in one dispatch. out was pre-zeroed in K1,
// so BOTH roles accumulate with f32 atomics -> order-independent, no race.
// ---------------------------------------------------------------------------
__global__ __launch_bounds__(256) void back_kernel(
    const float* __restrict__ h, const float* __restrict__ W2,
    const float* __restrict__ W2t, const float* __restrict__ b2,
    const unsigned* __restrict__ cnt, const uint2* __restrict__ list,
    float* __restrict__ out)
{
    const int y = blockIdx.y;
    const int tid = threadIdx.x;
    if (y < 8) {                                // ---- dense2 (atomic add)
        const int o0 = y * 4;
        __shared__ float wsm[4 * NC];
        if (tid < 128) {
            int o = tid >> 5, c = tid & 31;
            wsm[tid] = W2[((o0 + o) * NC + c) * TAPS + 40];
        }
        __syncthreads();
        const int pix = blockIdx.x * 256 + tid;
        float h0[NC];
#pragma unroll
        for (int c = 0; c < NC; ++c) h0[c] = h[c * NPIX + pix];
        float a0 = 0.f, a1 = 0.f, a2 = 0.f, a3 = 0.f;
#pragma unroll
        for (int c = 0; c < NC; ++c) {
            float hv = h0[c];
            a0 = fmaf(hv, wsm[0 * NC + c], a0);
            a1 = fmaf(hv, wsm[1 * NC + c], a1);
            a2 = fmaf(hv, wsm[2 * NC + c], a2);
            a3 = fmaf(hv, wsm[3 * NC + c], a3);
        }
        atomicAdd(&out[(o0 + 0) * NPIX + pix], a0 + b2[o0 + 0]);
        atomicAdd(&out[(o0 + 1) * NPIX + pix], a1 + b2[o0 + 1]);
        atomicAdd(&out[(o0 + 2) * NPIX + pix], a2 + b2[o0 + 2]);
        atomicAdd(&out[(o0 + 3) * NPIX + pix], a3 + b2[o0 + 3]);
        return;
    }
    // ---- y == 8: sparse2
    sparse_body(h, W2t, cnt, list, out,
                blockIdx.x * 256 + tid, 64 * 256);
}

// ---------------------------------------------------------------------------
// Fallback (proven path, 2 MB ws) in case ws is small. Takes W in original
// [o][c][tap] layout.
// ---------------------------------------------------------------------------
#define CHUNK 27
#define NCHUNK 3
#define KMIN 1e-6f
__global__ __launch_bounds__(256) void pac_layer_fuse(
    const float* __restrict__ in, const float* __restrict__ f,
    const float* __restrict__ Wt, const float* __restrict__ bias,
    float* __restrict__ out)
{
    __shared__ float wl[NC * CHUNK * 8];
    const int og = blockIdx.y;
    const int pix = blockIdx.x * 256 + threadIdx.x;
    const int h = pix >> 7, w = pix & (WW - 1);
    float acc[8];
#pragma unroll
    for (int i = 0; i < 8; ++i) acc[i] = 0.f;
    float fc[NC];
#pragma unroll
    for (int c = 0; c < NC; ++c) fc[c] = f[c * NPIX + pix];
    for (int ch = 0; ch < NCHUNK; ++ch) {
        __syncthreads();
        for (int idx = threadIdx.x; idx < NC * CHUNK * 8; idx += 256) {
            int t = idx % CHUNK;
            int c = (idx / CHUNK) % NC;
            int o = idx / (CHUNK * NC);
            wl[(c * CHUNK + t) * 8 + o] =
                Wt[(og * 8 + o) * (NC * TAPS) + c * TAPS + ch * CHUNK + t];
        }
        __syncthreads();
        for (int t = 0; t < CHUNK; ++t) {
            int tap = ch * CHUNK + t;
            int qh = h + (tap / KS) * DIL - PAD;
            int qw = w + (tap % KS) * DIL - PAD;
            bool valid = ((unsigned)qh < HH) & ((unsigned)qw < WW);
            int q = qh * WW + qw;
            float s = 0.f;
#pragma unroll
            for (int c = 0; c < NC; ++c) {
                float fn = valid ? f[c * NPIX + q] : 0.f;
                float d = fn - fc[c];
                s = fmaf(d, d, s);
            }
            float kv = __expf(-0.5f * s);
            if (__all((kv < KMIN) | (!valid))) continue;
            const float* wpp = &wl[t * 8];
#pragma unroll 8
            for (int c = 0; c < NC; ++c) {
                float v = valid ? in[c * NPIX + q] : 0.f;
                v *= kv;
#pragma unroll
                for (int o = 0; o < 8; ++o)
                    acc[o] = fmaf(v, wpp[c * CHUNK * 8 + o], acc[o]);
            }
        }
    }
#pragma unroll
    for (int o = 0; o < 8; ++o)
        out[(og * 8 + o) * NPIX + pix] = acc[o] + bias[og * 8 + o];
}

// ---------------------------------------------------------------------------
extern "C" void kernel_launch(void* const* d_in, const int* in_sizes, int n_in,
                              void* d_out, int out_size, void* d_ws, size_t ws_size,
                              hipStream_t stream)
{
    (void)in_sizes; (void)n_in; (void)out_size;
    const float* x  = (const float*)d_in[0];
    const float* f  = (const float*)d_in[1];
    const float* W1 = (const float*)d_in[2];
    const float* b1 = (const float*)d_in[3];
    const float* W2 = (const float*)d_in[4];
    const float* b2 = (const float*)d_in[5];
    float* out = (float*)d_out;

    float* ws = (float*)d_ws;
    float* h   = ws;                             // NO*NPIX floats (2 MB)
    float* W1t = ws + NO * NPIX;                 // NW
    float* W2t = W1t + NW;                       // NW
    unsigned* cnt = (unsigned*)(W2t + NW);       // 16 u32 (pad)
    uint2* list = (uint2*)(cnt + 16);            // CAP entries x 8 B
    const size_t need =
        (size_t)(NO * NPIX + 2 * NW + 16) * 4 + (size_t)CAP * 8;

    if (ws_size >= need) {
        zero_cnt_kernel<<<dim3(1), 64, 0, stream>>>(cnt);
        front_kernel<<<dim3(64, 51), 256, 0, stream>>>(
            x, f, W1, W2, b1, h, cnt, list, W1t, W2t, out);
        sparse1_kernel<<<dim3(128), 256, 0, stream>>>(x, W1t, cnt, list, h);
        back_kernel<<<dim3(64, 9), 256, 0, stream>>>(
            h, W2, W2t, b2, cnt, list, out);
    } else {
        float* hbuf = ws;
        pac_layer_fuse<<<dim3(64, 4), 256, 0, stream>>>(x, f, W1, b1, hbuf);
        pac_layer_fuse<<<dim3(64, 4), 256, 0, stream>>>(hbuf, f, W2, b2, out);
    }
}